// Round 17
// baseline (353.894 us; speedup 1.0000x reference)
//
#include <hip/hip_runtime.h>

#define D 64
#define K 1024
#define NROWS (32 * 4096)
#define NELEM (NROWS * D)
#define COMMIT 0.25f
#define DELTA 1.2e-4f
#define FLAGBIT 0x80000000u

typedef __attribute__((ext_vector_type(8))) short short8v;   // 8 bf16
typedef __attribute__((ext_vector_type(4))) float f32x4;
typedef unsigned long long u64;

static __device__ __forceinline__ float fence(float v) {
    asm("" : "+v"(v));
    return v;
}

// f32 -> bf16 bits, round-to-nearest-even (finite inputs only).
static __device__ __forceinline__ unsigned short f2bf(float f) {
    unsigned u = __float_as_uint(f);
    return (unsigned short)((u + 0x7FFFu + ((u >> 16) & 1u)) >> 16);
}

// Order-preserving float -> u32 map (handles negatives) and inverse.
static __device__ __forceinline__ float funmap(unsigned m) {
    return ((int)m < 0) ? __uint_as_float(m ^ 0x80000000u)
                        : __uint_as_float(~m);
}

// numpy pairwise_sum for n=64: 8 accumulators stride 8, then pairwise tree.
static __device__ __forceinline__ float np_sumsq64(const float* __restrict__ e) {
    float r[8];
#pragma unroll
    for (int j = 0; j < 8; ++j) r[j] = fence(e[j] * e[j]);
#pragma unroll
    for (int t = 1; t < 8; ++t)
#pragma unroll
        for (int j = 0; j < 8; ++j) r[j] = r[j] + fence(e[8 * t + j] * e[8 * t + j]);
    return ((r[0] + r[1]) + (r[2] + r[3])) + ((r[4] + r[5]) + (r[6] + r[7]));
}

// Bit-exact reference score: s = fl( fl(R+N) - 2*dot ), dot = ascending-i
// sequential FMA chain (validated absmax=0 in R2..R16).
static __device__ __forceinline__ float exact_score(
    const float* __restrict__ xrow, const float* __restrict__ erow, float R,
    float N) {
    float a = 0.0f;
#pragma unroll
    for (int i = 0; i < D; ++i) a = __builtin_fmaf(xrow[i], erow[i], a);
    return (R + N) - 2.0f * a;
}

// ---------------- Kernel 1: embedding prep (bf16 + norms) ----------------
__global__ void prep_emb_kernel(const float* __restrict__ emb,
                                float* __restrict__ enorm,
                                unsigned short* __restrict__ e_hi,
                                float* __restrict__ loss_slot) {
    int k = blockIdx.x * blockDim.x + threadIdx.x;
    if (k == 0) *loss_slot = 0.0f;
    if (k >= K) return;
    enorm[k] = np_sumsq64(emb + k * D);
    const float* e = emb + k * D;
#pragma unroll
    for (int i = 0; i < D; ++i) e_hi[k * D + i] = f2bf(e[i]);
}

// ---------------- Kernel 2: wave-independent single-pass MFMA argmin --------
// Each wave owns 32 rows (2 16-row tiles) x ALL 1024 codes; no inter-wave
// deps, no barriers until the final loss reduce. Per slot: P1 = min of
// m = (fmap(t) & ~0x3FF) | code10  (t quantized to ~1e-6 << eta=7.6e-6;
// monotone; quantized ties -> lowest code), M2 = second-min of m.
// gap(funmap(M2), funmap(P1)) > DELTA -> P1's code IS the reference argmin
// (R16-validated 18-sigma budget; quantization slop 1e-6 absorbed). Else:
// wave-parallel bit-exact rescan (lexicographic (s,k) = numpy first-index).
// Fused epilogue: gather + straight-through + loss.
__global__ __launch_bounds__(256, 1) void argmin_kernel(
    const float* __restrict__ x, const float* __restrict__ emb,
    const float* __restrict__ enorm, const unsigned short* __restrict__ e_hi,
    float* __restrict__ out_q, float* __restrict__ idx_f,
    float* __restrict__ loss_slot) {
    const int l = threadIdx.x & 63;
    const int w = threadIdx.x >> 6;
    const int col = l & 15;
    const int koff = (l >> 4) * 8;
    const int wrow = (blockIdx.x * 4 + w) * 32;  // wave-owned 32 rows

    __shared__ int lbid[4][32];
    __shared__ float wsum[4];

    // ---- A-fragments: bf16(x), named SSA. Layout (16x16x32): row = col,
    // k = h*32 + (l>>4)*8 + i; B uses the same permutation (R10-validated).
#define DECL_A(rt, h)                                                       \
    short8v A_##rt##_##h;                                                   \
    { const float* p = x + (size_t)(wrow + rt * 16 + col) * D + h * 32 + koff; \
      float4 q0 = *(const float4*)p, q1 = *(const float4*)(p + 4);          \
      A_##rt##_##h[0] = (short)f2bf(q0.x);                                  \
      A_##rt##_##h[1] = (short)f2bf(q0.y);                                  \
      A_##rt##_##h[2] = (short)f2bf(q0.z);                                  \
      A_##rt##_##h[3] = (short)f2bf(q0.w);                                  \
      A_##rt##_##h[4] = (short)f2bf(q1.x);                                  \
      A_##rt##_##h[5] = (short)f2bf(q1.y);                                  \
      A_##rt##_##h[6] = (short)f2bf(q1.z);                                  \
      A_##rt##_##h[7] = (short)f2bf(q1.w); }
    DECL_A(0, 0) DECL_A(0, 1) DECL_A(1, 0) DECL_A(1, 1)

    const unsigned short* __restrict__ bh = e_hi + col * D + koff;
    const float* __restrict__ bn = enorm + col;

    // per-slot state: 8 slots (2 rt x 4 r), named SSA u32
    unsigned P1_0 = ~0u, P1_1 = ~0u, P1_2 = ~0u, P1_3 = ~0u,
             P1_4 = ~0u, P1_5 = ~0u, P1_6 = ~0u, P1_7 = ~0u;
    unsigned M2_0 = ~0u, M2_1 = ~0u, M2_2 = ~0u, M2_3 = ~0u,
             M2_4 = ~0u, M2_5 = ~0u, M2_6 = ~0u, M2_7 = ~0u;

#define UPD(s, av)                                                          \
    { float t = __builtin_fmaf(-2.0f, (av), Nc);                            \
      unsigned u_ = __float_as_uint(t);                                     \
      unsigned m_ = ((int)u_ < 0) ? ~u_ : (u_ | 0x80000000u);               \
      m_ = (m_ & 0xFFFFFC00u) | code_;                                      \
      unsigned hi_ = P1_##s > m_ ? P1_##s : m_;                             \
      P1_##s = P1_##s < m_ ? P1_##s : m_;                                   \
      M2_##s = M2_##s < hi_ ? M2_##s : hi_; }

#define MFMA2(rt, sA, sB, sC, sD)                                           \
    { f32x4 acc = {0.f, 0.f, 0.f, 0.f};                                     \
      acc = __builtin_amdgcn_mfma_f32_16x16x32_bf16(A_##rt##_0, Bhi0, acc, 0, 0, 0); \
      acc = __builtin_amdgcn_mfma_f32_16x16x32_bf16(A_##rt##_1, Bhi1, acc, 0, 0, 0); \
      UPD(sA, acc[0]) UPD(sB, acc[1]) UPD(sC, acc[2]) UPD(sD, acc[3]) }

#define TILE(H0, H1, NN, NT)                                                \
    { const short8v Bhi0 = H0, Bhi1 = H1;                                   \
      const float Nc = NN;                                                  \
      const unsigned code_ = ((unsigned)(NT) << 4) | (unsigned)col;         \
      MFMA2(0, 0, 1, 2, 3) MFMA2(1, 4, 5, 6, 7) }

#define LOADT(H0, H1, NN, off)                                              \
    H0 = *(const short8v*)(bh + (size_t)(off) * 1024);                      \
    H1 = *(const short8v*)(bh + (size_t)(off) * 1024 + 32);                 \
    NN = bn[(off) * 16];

    // ---- single pass over all 64 code-tiles, ping-pong double buffer ----
    {
        short8v pH0, pH1, qH0, qH1;
        float pN, qN;
        LOADT(pH0, pH1, pN, 0)
        for (int nt = 0; nt < 64; nt += 2) {
            LOADT(qH0, qH1, qN, nt + 1)
            TILE(pH0, pH1, pN, nt)
            const int nxt = (nt + 2 < 64) ? nt + 2 : 63;
            LOADT(pH0, pH1, pN, nxt)
            TILE(qH0, qH1, qN, nt + 1)
        }
    }

    // ---- 16-lane butterfly per slot (C/D: col=l&15, row=(l>>4)*4+r) ----
#define BSTEP(s, off)                                                       \
    { unsigned po_ = __shfl_xor(P1_##s, off);                               \
      unsigned mo_ = __shfl_xor(M2_##s, off);                               \
      unsigned hi_ = P1_##s > po_ ? P1_##s : po_;                           \
      P1_##s = P1_##s < po_ ? P1_##s : po_;                                 \
      unsigned mm_ = M2_##s < mo_ ? M2_##s : mo_;                           \
      M2_##s = mm_ < hi_ ? mm_ : hi_; }
#define BFLY(s) BSTEP(s, 1) BSTEP(s, 2) BSTEP(s, 4) BSTEP(s, 8)
    BFLY(0) BFLY(1) BFLY(2) BFLY(3) BFLY(4) BFLY(5) BFLY(6) BFLY(7)

    // ---- per-row result + ambiguity flag -> wave-local LDS ----
    if (col == 0) {
        const int g = l >> 4;
#define WRS(s)                                                              \
        { float t1 = funmap(P1_##s & 0xFFFFFC00u);                          \
          float t2 = funmap(M2_##s & 0xFFFFFC00u);                          \
          int v = (int)(P1_##s & 0x3FFu);                                   \
          if (t2 - t1 <= DELTA) v |= (int)FLAGBIT;                          \
          lbid[w][((s) / 4) * 16 + g * 4 + ((s) % 4)] = v; }
        WRS(0) WRS(1) WRS(2) WRS(3) WRS(4) WRS(5) WRS(6) WRS(7)
    }
    asm volatile("s_waitcnt lgkmcnt(0)" ::: "memory");  // wave-local LDS sync
    __builtin_amdgcn_sched_barrier(0);

    // ---- rescue: flagged rows get a wave-parallel bit-exact rescan ----
    for (int rl = 0; rl < 32; ++rl) {
        int v = lbid[w][rl];  // wave-uniform read
        if ((unsigned)v & FLAGBIT) {
            const float* __restrict__ xrow = x + (size_t)(wrow + rl) * D;
            const float R = np_sumsq64(xrow);
            u64 best = ~0ULL;
            for (int j = 0; j < 16; ++j) {
                const int c = j * 64 + l;
                float sE = exact_score(xrow, emb + ((size_t)c << 6), R,
                                       enorm[c]);
                // sE ~ 64 > 0 -> direct bit order; low32 = code -> first-idx
                u64 pk = ((u64)__float_as_uint(sE) << 32) | (unsigned)c;
                best = pk < best ? pk : best;
            }
#pragma unroll
            for (int off = 1; off < 64; off <<= 1) {
                u64 po = __shfl_xor(best, off);
                best = po < best ? po : best;
            }
            if (l == 0) lbid[w][rl] = (int)(best & 0x3FFu);
        }
    }
    asm volatile("s_waitcnt lgkmcnt(0)" ::: "memory");
    __builtin_amdgcn_sched_barrier(0);

    // ---- indices out ----
    if (l < 32) idx_f[wrow + l] = (float)(lbid[w][l] & 0x3FF);

    // ---- fused epilogue: gather + straight-through + loss (wave-local) ----
    float lsum = 0.f;
#pragma unroll
    for (int rr = 0; rr < 4; ++rr) {
        const int rl = rr * 8 + (l >> 3);
        const int bk = lbid[w][rl] & 0x3FF;
        const int d0 = (l & 7) * 8;
        const float4* xq = (const float4*)(x + (size_t)(wrow + rl) * D + d0);
        const float4* eq = (const float4*)(emb + ((size_t)bk << 6) + d0);
        float4* oq = (float4*)(out_q + (size_t)(wrow + rl) * D + d0);
#pragma unroll
        for (int i = 0; i < 2; ++i) {
            float4 xv = xq[i];
            float4 ev = eq[i];
            float dx = ev.x - xv.x, dy = ev.y - xv.y, dz = ev.z - xv.z,
                  dw = ev.w - xv.w;
            float4 o;
            o.x = xv.x + dx;
            o.y = xv.y + dy;
            o.z = xv.z + dz;
            o.w = xv.w + dw;
            oq[i] = o;
            lsum = __builtin_fmaf(dx, dx, lsum);
            lsum = __builtin_fmaf(dy, dy, lsum);
            lsum = __builtin_fmaf(dz, dz, lsum);
            lsum = __builtin_fmaf(dw, dw, lsum);
        }
    }
#pragma unroll
    for (int o = 32; o > 0; o >>= 1) lsum += __shfl_xor(lsum, o);
    if (l == 0) wsum[w] = lsum;
    __syncthreads();  // the only block barrier: loss combine
    if (threadIdx.x == 0)
        atomicAdd(loss_slot, ((wsum[0] + wsum[1]) + (wsum[2] + wsum[3])) *
                                 ((1.0f + COMMIT) / (float)NELEM));
}

extern "C" void kernel_launch(void* const* d_in, const int* in_sizes, int n_in,
                              void* d_out, int out_size, void* d_ws,
                              size_t ws_size, hipStream_t stream) {
    const float* x = (const float*)d_in[0];    // [32,4096,64] f32
    const float* emb = (const float*)d_in[1];  // [1024,64] f32

    float* out = (float*)d_out;
    float* loss_slot = out;              // out[0]
    float* out_q = out + 1;              // out[1 .. 1+NELEM)
    float* idx_f = out + 1 + NELEM;      // indices as f32

    // workspace layout (16B-aligned slabs)
    float* enorm = (float*)d_ws;                                    // 4 KB
    unsigned short* e_hi = (unsigned short*)((char*)d_ws + 4096);   // 128 KB

    prep_emb_kernel<<<(K + 255) / 256, 256, 0, stream>>>(emb, enorm, e_hi,
                                                         loss_slot);
    argmin_kernel<<<NROWS / 128, 256, 0, stream>>>(x, emb, enorm, e_hi, out_q,
                                                   idx_f, loss_slot);
}

// Round 18
// 115.267 us; speedup vs baseline: 3.0702x; 3.0702x over previous
//
#include <hip/hip_runtime.h>

#define D 64
#define K 1024
#define NROWS (32 * 4096)
#define NELEM (NROWS * D)
#define COMMIT 0.25f
#define DELTA 1.2e-4f

typedef __attribute__((ext_vector_type(8))) short short8v;   // 8 bf16
typedef __attribute__((ext_vector_type(4))) float f32x4;
typedef unsigned long long u64;

#define FORSLOT(M) M(0) M(1) M(2) M(3) M(4) M(5) M(6) M(7) \
                   M(8) M(9) M(10) M(11) M(12) M(13) M(14) M(15)

static __device__ __forceinline__ float fence(float v) {
    asm("" : "+v"(v));
    return v;
}

// f32 -> bf16 bits, round-to-nearest-even (finite inputs only).
static __device__ __forceinline__ unsigned short f2bf(float f) {
    unsigned u = __float_as_uint(f);
    return (unsigned short)((u + 0x7FFFu + ((u >> 16) & 1u)) >> 16);
}

// numpy pairwise_sum for n=64: 8 accumulators stride 8, then pairwise tree.
static __device__ __forceinline__ float np_sumsq64(const float* __restrict__ e) {
    float r[8];
#pragma unroll
    for (int j = 0; j < 8; ++j) r[j] = fence(e[j] * e[j]);
#pragma unroll
    for (int t = 1; t < 8; ++t)
#pragma unroll
        for (int j = 0; j < 8; ++j) r[j] = r[j] + fence(e[8 * t + j] * e[8 * t + j]);
    return ((r[0] + r[1]) + (r[2] + r[3])) + ((r[4] + r[5]) + (r[6] + r[7]));
}

// Bit-exact reference score: s = fl( fl(R+N) - 2*dot ), dot = ascending-i
// sequential FMA chain (validated absmax=0 in R2..R17).
static __device__ __forceinline__ float exact_score(
    const float* __restrict__ xrow, const float* __restrict__ erow, float R,
    float N) {
    float a = 0.0f;
#pragma unroll
    for (int i = 0; i < D; ++i) a = __builtin_fmaf(xrow[i], erow[i], a);
    return (R + N) - 2.0f * a;
}

// ---------------- Kernel 1: embedding prep (bf16 + norms) ----------------
__global__ void prep_emb_kernel(const float* __restrict__ emb,
                                float* __restrict__ enorm,
                                unsigned short* __restrict__ e_hi,
                                float* __restrict__ loss_slot) {
    int k = blockIdx.x * blockDim.x + threadIdx.x;
    if (k == 0) *loss_slot = 0.0f;
    if (k >= K) return;
    enorm[k] = np_sumsq64(emb + k * D);
    const float* e = emb + k * D;
#pragma unroll
    for (int i = 0; i < D; ++i) e_hi[k * D + i] = f2bf(e[i]);
}

// ---------------- Kernel 2: 2-pass single-product MFMA argmin ---------------
// EXACT R16 algorithm (109.9 us, absmax=0). One change: depth-2 prefetch via
// 3 rotating named buffer sets, fully unrolled 16-step schedule, both passes.
// R16's residual was per-tile L2 latency (~200cyc) vs tile compute (~104cyc)
// with only 1-deep ping-pong; depth-2 keeps ~2 tiles of loads in flight.
// EMPIRICAL LAW (R10/13/16 fast vs R11/12/17 slow): in-loop post-MFMA work
// must stay <= 2 simple float ops per acc element (fmaf+fminf here); all
// bit-pack/min2/index state machines belong OUTSIDE the MFMA loop.
__global__ __launch_bounds__(256, 1) void argmin_kernel(
    const float* __restrict__ x, const float* __restrict__ emb,
    const float* __restrict__ enorm, const unsigned short* __restrict__ e_hi,
    float* __restrict__ out_q, float* __restrict__ idx_f,
    float* __restrict__ loss_slot) {
    const int l = threadIdx.x & 63;
    const int w = threadIdx.x >> 6;
    const int rowbase = blockIdx.x * 64;
    const int cbase = w * 256;

    __shared__ float wminA[4][64];
    __shared__ float gmin[64];
    __shared__ int cnt[64];
    __shared__ int clist[64][8];
    __shared__ int bidx[64];
    __shared__ float wsum[4];

    // ---- A-fragments: bf16(x), named SSA short8v. Layout (16x16x32):
    // row = l&15, k = h*32 + (l>>4)*8 + i; B uses the same permutation.
#define DECL_A(rt, h)                                                       \
    short8v Ahi_##rt##_##h;                                                 \
    { const float* p = x + (size_t)(rowbase + rt * 16 + (l & 15)) * D +     \
                       h * 32 + (l >> 4) * 8;                               \
      float4 q0 = *(const float4*)p, q1 = *(const float4*)(p + 4);          \
      Ahi_##rt##_##h[0] = (short)f2bf(q0.x);                                \
      Ahi_##rt##_##h[1] = (short)f2bf(q0.y);                                \
      Ahi_##rt##_##h[2] = (short)f2bf(q0.z);                                \
      Ahi_##rt##_##h[3] = (short)f2bf(q0.w);                                \
      Ahi_##rt##_##h[4] = (short)f2bf(q1.x);                                \
      Ahi_##rt##_##h[5] = (short)f2bf(q1.y);                                \
      Ahi_##rt##_##h[6] = (short)f2bf(q1.z);                                \
      Ahi_##rt##_##h[7] = (short)f2bf(q1.w); }
    DECL_A(0, 0) DECL_A(0, 1) DECL_A(1, 0) DECL_A(1, 1)
    DECL_A(2, 0) DECL_A(2, 1) DECL_A(3, 0) DECL_A(3, 1)

    const int koff = (l >> 4) * 8;
    const unsigned short* __restrict__ bh =
        e_hi + (size_t)(cbase + (l & 15)) * D + koff;
    const float* __restrict__ bn = enorm + cbase + (l & 15);

    // 3 rotating B-buffer sets (depth-2 prefetch)
    short8v bH0_0, bH1_0, bH0_1, bH1_1, bH0_2, bH1_2;
    float bN_0, bN_1, bN_2;

#define LOADT(u, off)                                                       \
    bH0_##u = *(const short8v*)(bh + (size_t)(off) * 1024);                 \
    bH1_##u = *(const short8v*)(bh + (size_t)(off) * 1024 + 32);            \
    bN_##u = bn[(off) * 16];

    // slot s = rt*4 + r maps to row (s/4)*16 + (l>>4)*4 + (s%4)
#define SLOTROW(s) (((s) / 4) * 16 + (l >> 4) * 4 + ((s) % 4))

    // =================== PASS A: fminf min, depth-2 prefetch ================
#define DECL_MA(s) float mA_##s = 3.402823466e+38f;
    FORSLOT(DECL_MA)
#define MFMA2A(rt, sA, sB, sC, sD)                                          \
    { f32x4 acc = {0.f, 0.f, 0.f, 0.f};                                     \
      acc = __builtin_amdgcn_mfma_f32_16x16x32_bf16(Ahi_##rt##_0, Bhi0, acc, 0, 0, 0); \
      acc = __builtin_amdgcn_mfma_f32_16x16x32_bf16(Ahi_##rt##_1, Bhi1, acc, 0, 0, 0); \
      mA_##sA = fminf(mA_##sA, __builtin_fmaf(-2.0f, acc[0], Nc));          \
      mA_##sB = fminf(mA_##sB, __builtin_fmaf(-2.0f, acc[1], Nc));          \
      mA_##sC = fminf(mA_##sC, __builtin_fmaf(-2.0f, acc[2], Nc));          \
      mA_##sD = fminf(mA_##sD, __builtin_fmaf(-2.0f, acc[3], Nc)); }
#define TILEA(u)                                                            \
    { const short8v Bhi0 = bH0_##u, Bhi1 = bH1_##u;                         \
      const float Nc = bN_##u;                                              \
      MFMA2A(0, 0, 1, 2, 3) MFMA2A(1, 4, 5, 6, 7)                           \
      MFMA2A(2, 8, 9, 10, 11) MFMA2A(3, 12, 13, 14, 15) }
    // schedule: tile nt uses buf nt%3; tile nt+2 loads into buf (nt+2)%3
    LOADT(0, 0) LOADT(1, 1)
    LOADT(2, 2)  TILEA(0)
    LOADT(0, 3)  TILEA(1)
    LOADT(1, 4)  TILEA(2)
    LOADT(2, 5)  TILEA(0)
    LOADT(0, 6)  TILEA(1)
    LOADT(1, 7)  TILEA(2)
    LOADT(2, 8)  TILEA(0)
    LOADT(0, 9)  TILEA(1)
    LOADT(1, 10) TILEA(2)
    LOADT(2, 11) TILEA(0)
    LOADT(0, 12) TILEA(1)
    LOADT(1, 13) TILEA(2)
    LOADT(2, 14) TILEA(0)
    LOADT(0, 15) TILEA(1)
    TILEA(2)
    TILEA(0)

    // C/D layout: col = l&15 (code), row-group = 16 contiguous lanes.
#define BFA(s)                                                              \
    mA_##s = fminf(mA_##s, __shfl_xor(mA_##s, 1));                          \
    mA_##s = fminf(mA_##s, __shfl_xor(mA_##s, 2));                          \
    mA_##s = fminf(mA_##s, __shfl_xor(mA_##s, 4));                          \
    mA_##s = fminf(mA_##s, __shfl_xor(mA_##s, 8));
    FORSLOT(BFA)
#define WRA(s) if ((l & 15) == 0) wminA[w][SLOTROW(s)] = mA_##s;
    FORSLOT(WRA)
    __syncthreads();
    if (threadIdx.x < 64) {
        gmin[threadIdx.x] =
            fminf(fminf(wminA[0][threadIdx.x], wminA[1][threadIdx.x]),
                  fminf(wminA[2][threadIdx.x], wminA[3][threadIdx.x]));
        cnt[threadIdx.x] = 0;
    }
    __syncthreads();

    // =================== PASS B: candidate collection, depth-2 ==============
#define DECL_T(s) const float thr_##s = gmin[SLOTROW(s)] + DELTA;
    FORSLOT(DECL_T)
#define CHK(s, tval)                                                        \
    { float t = __builtin_fmaf(-2.0f, (tval), Nc);                          \
      if (t <= thr_##s) {                                                   \
          int row = SLOTROW(s);                                             \
          int pos = atomicAdd(&cnt[row], 1);                                \
          if (pos < 8) clist[row][pos] = code;                              \
      } }
#define MFMA2B(rt, sA, sB, sC, sD)                                          \
    { f32x4 acc = {0.f, 0.f, 0.f, 0.f};                                     \
      acc = __builtin_amdgcn_mfma_f32_16x16x32_bf16(Ahi_##rt##_0, Bhi0, acc, 0, 0, 0); \
      acc = __builtin_amdgcn_mfma_f32_16x16x32_bf16(Ahi_##rt##_1, Bhi1, acc, 0, 0, 0); \
      CHK(sA, acc[0]) CHK(sB, acc[1]) CHK(sC, acc[2]) CHK(sD, acc[3]) }
#define TILEB(u, NT)                                                        \
    { const short8v Bhi0 = bH0_##u, Bhi1 = bH1_##u;                         \
      const float Nc = bN_##u;                                              \
      const int code = cbase + (l & 15) + (NT) * 16;                        \
      MFMA2B(0, 0, 1, 2, 3) MFMA2B(1, 4, 5, 6, 7)                           \
      MFMA2B(2, 8, 9, 10, 11) MFMA2B(3, 12, 13, 14, 15) }
    LOADT(0, 0) LOADT(1, 1)
    LOADT(2, 2)  TILEB(0, 0)
    LOADT(0, 3)  TILEB(1, 1)
    LOADT(1, 4)  TILEB(2, 2)
    LOADT(2, 5)  TILEB(0, 3)
    LOADT(0, 6)  TILEB(1, 4)
    LOADT(1, 7)  TILEB(2, 5)
    LOADT(2, 8)  TILEB(0, 6)
    LOADT(0, 9)  TILEB(1, 7)
    LOADT(1, 10) TILEB(2, 8)
    LOADT(2, 11) TILEB(0, 9)
    LOADT(0, 12) TILEB(1, 10)
    LOADT(1, 13) TILEB(2, 11)
    LOADT(2, 14) TILEB(0, 12)
    LOADT(0, 15) TILEB(1, 13)
    TILEB(2, 14)
    TILEB(0, 15)
    __syncthreads();

    // ---- select / rescue (1 thread per row), bit-exact final answer ----
    if (threadIdx.x < 64) {
        const int row = threadIdx.x;
        const int n = cnt[row];
        int bk;
        if (n == 1) {
            bk = clist[row][0];
        } else {
            const float* xrow = x + (size_t)(rowbase + row) * D;
            const float R = np_sumsq64(xrow);
            float sb = 3.402823466e+38f;
            int kb = 0x7fffffff;
            if (n <= 8) {
                for (int i = 0; i < n; ++i) {
                    int c = clist[row][i];
                    float s = exact_score(xrow, emb + ((size_t)c << 6), R,
                                          enorm[c]);
                    if (s < sb || (s == sb && c < kb)) { sb = s; kb = c; }
                }
            } else {  // clist overflow: full exact scan (essentially never)
                for (int c = 0; c < K; ++c) {
                    float s = exact_score(xrow, emb + ((size_t)c << 6), R,
                                          enorm[c]);
                    if (s < sb || (s == sb && c < kb)) { sb = s; kb = c; }
                }
            }
            bk = kb;
        }
        bidx[row] = bk;
        idx_f[rowbase + row] = (float)bk;
    }
    __syncthreads();

    // ---- fused epilogue: gather + straight-through + loss ----
    {
        const int row = threadIdx.x >> 2;
        const int d0 = (threadIdx.x & 3) * 16;
        const int bk = bidx[row];
        const float4* xq = (const float4*)(x + (size_t)(rowbase + row) * D + d0);
        const float4* eq = (const float4*)(emb + ((size_t)bk << 6) + d0);
        float4* oq = (float4*)(out_q + (size_t)(rowbase + row) * D + d0);
        float lsum = 0.f;
#pragma unroll
        for (int i = 0; i < 4; ++i) {
            float4 xv = xq[i];
            float4 ev = eq[i];
            float dx = ev.x - xv.x, dy = ev.y - xv.y, dz = ev.z - xv.z,
                  dw = ev.w - xv.w;
            float4 o;
            o.x = xv.x + dx;
            o.y = xv.y + dy;
            o.z = xv.z + dz;
            o.w = xv.w + dw;
            oq[i] = o;
            lsum = __builtin_fmaf(dx, dx, lsum);
            lsum = __builtin_fmaf(dy, dy, lsum);
            lsum = __builtin_fmaf(dz, dz, lsum);
            lsum = __builtin_fmaf(dw, dw, lsum);
        }
#pragma unroll
        for (int o = 32; o > 0; o >>= 1) lsum += __shfl_xor(lsum, o);
        if (l == 0) wsum[w] = lsum;
        __syncthreads();
        if (threadIdx.x == 0)
            atomicAdd(loss_slot, ((wsum[0] + wsum[1]) + (wsum[2] + wsum[3])) *
                                     ((1.0f + COMMIT) / (float)NELEM));
    }
}

extern "C" void kernel_launch(void* const* d_in, const int* in_sizes, int n_in,
                              void* d_out, int out_size, void* d_ws,
                              size_t ws_size, hipStream_t stream) {
    const float* x = (const float*)d_in[0];    // [32,4096,64] f32
    const float* emb = (const float*)d_in[1];  // [1024,64] f32

    float* out = (float*)d_out;
    float* loss_slot = out;              // out[0]
    float* out_q = out + 1;              // out[1 .. 1+NELEM)
    float* idx_f = out + 1 + NELEM;      // indices as f32

    // workspace layout (16B-aligned slabs)
    float* enorm = (float*)d_ws;                                    // 4 KB
    unsigned short* e_hi = (unsigned short*)((char*)d_ws + 4096);   // 128 KB

    prep_emb_kernel<<<(K + 255) / 256, 256, 0, stream>>>(emb, enorm, e_hi,
                                                         loss_slot);
    argmin_kernel<<<NROWS / 64, 256, 0, stream>>>(x, emb, enorm, e_hi, out_q,
                                                  idx_f, loss_slot);
}